// Round 1
// baseline (2273.822 us; speedup 1.0000x reference)
//
#include <hip/hip_runtime.h>
#include <hip/hip_bf16.h>
#include <math.h>

typedef __bf16 bf16_t;
typedef __bf16 bf16x2_t __attribute__((ext_vector_type(2)));
typedef __bf16 bf16x4_t __attribute__((ext_vector_type(4)));
typedef __bf16 bf16x8_t __attribute__((ext_vector_type(8)));
typedef float f32x4_t __attribute__((ext_vector_type(4)));

#define B_N 1024
#define L_N 1024
#define T_N 32
#define H_N 2048
#define K_TOP 64
#define O_N 256
#define NCOL (T_N * H_N) /* 65536 */

// ---------------- conversion: x -> bf16 ----------------
__global__ __launch_bounds__(256) void cvt_x_kernel(const float* __restrict__ x,
                                                    bf16_t* __restrict__ xb) {
  int i = (blockIdx.x * 256 + threadIdx.x) * 4;
  float4 v = *(const float4*)(x + i);
  bf16x4_t o;
  o[0] = (bf16_t)v.x; o[1] = (bf16_t)v.y; o[2] = (bf16_t)v.z; o[3] = (bf16_t)v.w;
  *(bf16x4_t*)(xb + i) = o;
}

// -------- conversion+transpose: Wt [T,L,H] f32 -> WT [T,H,L] bf16 --------
__global__ __launch_bounds__(256) void cvt_w_kernel(const float* __restrict__ W,
                                                    bf16_t* __restrict__ WT) {
  __shared__ float tile[64][65];
  int t = blockIdx.z;
  int h0 = blockIdx.x * 64;
  int l0 = blockIdx.y * 64;
  const float* src = W + (size_t)t * L_N * H_N;
  int hx = threadIdx.x & 63;
  int ly = threadIdx.x >> 6;
#pragma unroll
  for (int r = 0; r < 64; r += 4)
    tile[ly + r][hx] = src[(size_t)(l0 + ly + r) * H_N + h0 + hx];
  __syncthreads();
  bf16_t* dst = WT + (size_t)t * H_N * L_N;
  int lx = (threadIdx.x & 31) * 2;
  int hy = threadIdx.x >> 5;
#pragma unroll
  for (int r = 0; r < 64; r += 8) {
    int h = hy + r;
    bf16x2_t o;
    o[0] = (bf16_t)tile[lx][h];
    o[1] = (bf16_t)tile[lx + 1][h];
    *(bf16x2_t*)(dst + (size_t)(h0 + h) * L_N + l0 + lx) = o;
  }
}

// ---------------- GEMM1: hidden[b, t*2048+h] = sum_l x[b,l]*W[t,l,h] ----------------
#define BM 128
#define BN 128
#define BK 32

__device__ __forceinline__ void async_load16(const void* g, void* l) {
  __builtin_amdgcn_global_load_lds((const __attribute__((address_space(1))) void*)g,
                                   (__attribute__((address_space(3))) void*)l,
                                   16, 0, 0);
}

template <typename HT>
__global__ __launch_bounds__(256) void gemm1_kernel(const bf16_t* __restrict__ Xb,
                                                    const bf16_t* __restrict__ WT,
                                                    HT* __restrict__ hidden) {
  __shared__ bf16_t As[BM][BK]; // [m][k], row = 64 B
  __shared__ bf16_t Bs[BN][BK]; // [n][k], row = 64 B  (WT is already [n][k] in global)
  int tid = threadIdx.x;
  int wave = tid >> 6;
  int lane = tid & 63;
  int bid = blockIdx.x;
  int m0 = (bid & 7) * BM;      // 8 row tiles over B=1024
  int nbase = (bid >> 3) * BN;  // 512 col tiles over T*H=65536

  const bf16_t* Aptr = Xb + (size_t)m0 * L_N;
  const bf16_t* Bptr = WT + (size_t)nbase * L_N;

  // staging: lane i copies 16 B; wave covers 16 contiguous 64 B LDS rows
  int srow = lane >> 2;
  int scol = lane & 3;
  size_t soff = (size_t)(wave * 16 + srow) * L_N + scol * 8;

  f32x4_t acc[4][4];
  f32x4_t zero = {0.f, 0.f, 0.f, 0.f};
#pragma unroll
  for (int i = 0; i < 4; i++)
#pragma unroll
    for (int j = 0; j < 4; j++) acc[i][j] = zero;

  int wm = wave >> 1, wn = wave & 1;
  int fr = lane & 15;
  int fq = lane >> 4;

  for (int k0 = 0; k0 < L_N; k0 += BK) {
    const bf16_t* ga = Aptr + soff + k0;
    const bf16_t* gb = Bptr + soff + k0;
    async_load16(ga, &As[wave * 16][0]);
    async_load16(ga + 64 * L_N, &As[64 + wave * 16][0]);
    async_load16(gb, &Bs[wave * 16][0]);
    async_load16(gb + 64 * L_N, &Bs[64 + wave * 16][0]);
    __syncthreads();
    bf16x8_t af[4], bfv[4];
#pragma unroll
    for (int i = 0; i < 4; i++)
      af[i] = *(const bf16x8_t*)&As[wm * 64 + i * 16 + fr][fq * 8];
#pragma unroll
    for (int j = 0; j < 4; j++)
      bfv[j] = *(const bf16x8_t*)&Bs[wn * 64 + j * 16 + fr][fq * 8];
#pragma unroll
    for (int i = 0; i < 4; i++)
#pragma unroll
      for (int j = 0; j < 4; j++)
        acc[i][j] = __builtin_amdgcn_mfma_f32_16x16x32_bf16(af[i], bfv[j], acc[i][j], 0, 0, 0);
    __syncthreads();
  }

  // C/D layout: col = lane&15, row = (lane>>4)*4 + r  [verified m89/m91]
#pragma unroll
  for (int i = 0; i < 4; i++) {
    int gm = m0 + wm * 64 + i * 16 + fq * 4;
#pragma unroll
    for (int j = 0; j < 4; j++) {
      int gn = nbase + wn * 64 + j * 16 + fr;
      HT* outp = hidden + (size_t)gm * NCOL + gn;
#pragma unroll
      for (int r = 0; r < 4; r++) outp[(size_t)r * NCOL] = (HT)acc[i][j][r];
    }
  }
}

// ---------------- helpers shared by the tail kernels ----------------

__device__ __forceinline__ float wave_reduce_sum(float v) {
#pragma unroll
  for (int off = 32; off > 0; off >>= 1) v += __shfl_xor(v, off);
  return v;
}

// order-preserving float->uint key and inverse
__device__ __forceinline__ unsigned f2key(float f) {
  unsigned u = __float_as_uint(f);
  return u ^ ((u >> 31) ? 0xFFFFFFFFu : 0x80000000u);
}
__device__ __forceinline__ float key2f(unsigned k) {
  return __uint_as_float(k ^ ((k >> 31) ? 0x80000000u : 0xFFFFFFFFu));
}

__device__ __forceinline__ int lanes_below(unsigned long long m) {
  return (int)__builtin_amdgcn_mbcnt_hi((unsigned)(m >> 32),
                                        __builtin_amdgcn_mbcnt_lo((unsigned)m, 0u));
}

// f32 path: 2 batches of 4x16B loads — keeps staging peak at 16 VGPRs so the
// whole select kernel fits the (256,6) = ~85-VGPR budget without spilling.
__device__ __forceinline__ void load_keys(const float* __restrict__ row, int lane,
                                          unsigned key[32]) {
  const float4* r4 = (const float4*)row;
#pragma unroll
  for (int h = 0; h < 2; h++) {
    float4 v[4];
#pragma unroll
    for (int q = 0; q < 4; q++) v[q] = r4[lane + 64 * (h * 4 + q)];
#pragma unroll
    for (int q = 0; q < 4; q++) {
      int o = (h * 4 + q) * 4;
      key[o + 0] = f2key(v[q].x);
      key[o + 1] = f2key(v[q].y);
      key[o + 2] = f2key(v[q].z);
      key[o + 3] = f2key(v[q].w);
    }
  }
}

__device__ __forceinline__ void load_keys(const bf16_t* __restrict__ row, int lane,
                                          unsigned key[32]) {
  const bf16x8_t* r8 = (const bf16x8_t*)row;
#pragma unroll
  for (int h = 0; h < 2; h++) {
    bf16x8_t v[2];
#pragma unroll
    for (int q = 0; q < 2; q++) v[q] = r8[lane + 64 * (h * 2 + q)];
#pragma unroll
    for (int q = 0; q < 2; q++)
#pragma unroll
      for (int j = 0; j < 8; j++) key[(h * 2 + q) * 8 + j] = f2key((float)v[q][j]);
  }
}

// ---------------- kernel A: top-64 select + sort -> g[B,T,64] f32 ----------------
// Split from the old fused tail: select needs key[32] (~70 VGPR peak) while
// dense+GELU+LN needs ~30; fused they forced 128 VGPR -> ~2 waves/SIMD and a
// latency-bound 510 us (VALUBusy 19%, HBM 11%). Split: select at (256,6).
template <typename HT>
__global__ __launch_bounds__(256, 6) void topk_select_kernel(
    const HT* __restrict__ hidden, float* __restrict__ g_out) {
  __shared__ unsigned slots[4][K_TOP];
  int t = blockIdx.y;
  int wave = threadIdx.x >> 6;
  int lane = threadIdx.x & 63;
  int b = blockIdx.x * 4 + wave;

  unsigned key[32];
  load_keys(hidden + (size_t)b * NCOL + (size_t)t * H_N, lane, key);

  // exact 64th-largest key: largest thr with count(key >= thr) >= 64
  unsigned thr = 0;
  for (int bit = 31; bit >= 0; --bit) {
    unsigned cand = thr | (1u << bit);
    int c = 0;
#pragma unroll
    for (int i = 0; i < 32; i++) c += (int)__popcll(__ballot(key[i] >= cand));
    if (c >= K_TOP) thr = cand; // wave-uniform
  }

  // compaction via ballot prefix (no atomics, wave-local LDS only)
  int base = 0;
#pragma unroll
  for (int i = 0; i < 32; i++) {
    bool p = key[i] > thr;
    unsigned long long m = __ballot(p);
    if (p) slots[wave][base + lanes_below(m)] = key[i];
    base += (int)__popcll(m);
  }
#pragma unroll
  for (int i = 0; i < 32; i++) {
    bool p = key[i] == thr;
    unsigned long long m = __ballot(p);
    if (p) {
      int pos = base + lanes_below(m);
      if (pos < K_TOP) slots[wave][pos] = key[i];
    }
    base += (int)__popcll(m);
  }

  // 64-lane register bitonic sort, descending (unsigned keys)
  unsigned g = slots[wave][lane];
#pragma unroll
  for (int k = 2; k <= 64; k <<= 1) {
#pragma unroll
    for (int j = k >> 1; j > 0; j >>= 1) {
      unsigned other = (unsigned)__shfl_xor((int)g, j);
      bool keep_max = (((lane & k) == 0) != ((lane & j) != 0));
      unsigned mx = g > other ? g : other;
      unsigned mn = g > other ? other : g;
      g = keep_max ? mx : mn;
    }
  }
  g_out[((size_t)b * T_N + t) * K_TOP + lane] = key2f(g);
}

// ---------------- kernel B: dense + GELU + LN from g ----------------

__device__ __forceinline__ void gelu_ln_store(float y0, float y1, float y2, float y3,
                                              const float* __restrict__ gm,
                                              const float* __restrict__ bt,
                                              float* __restrict__ op, int lane) {
  const float is2 = 0.70710678118654752f;
  y0 = 0.5f * y0 * (1.f + erff(y0 * is2));
  y1 = 0.5f * y1 * (1.f + erff(y1 * is2));
  y2 = 0.5f * y2 * (1.f + erff(y2 * is2));
  y3 = 0.5f * y3 * (1.f + erff(y3 * is2));
  float mean = wave_reduce_sum(y0 + y1 + y2 + y3) * (1.f / 256.f);
  float d0 = y0 - mean, d1 = y1 - mean, d2 = y2 - mean, d3 = y3 - mean;
  float var = wave_reduce_sum(d0 * d0 + d1 * d1 + d2 * d2 + d3 * d3) * (1.f / 256.f);
  float rstd = rsqrtf(var + 1e-6f);
  op[lane] = d0 * rstd * gm[lane] + bt[lane];
  op[64 + lane] = d1 * rstd * gm[64 + lane] + bt[64 + lane];
  op[128 + lane] = d2 * rstd * gm[128 + lane] + bt[128 + lane];
  op[192 + lane] = d3 * rstd * gm[192 + lane] + bt[192 + lane];
}

// ~30 VGPRs -> (256,8) for full occupancy. Each wave handles 2 rows of the
// same t so each Wd row load (4 dwords/lane) is reused twice (halves VMEM issue).
__global__ __launch_bounds__(256, 8) void dense_tail_kernel(
    const float* __restrict__ g_in, const float* __restrict__ Wd,
    const float* __restrict__ bd, const float* __restrict__ gamma,
    const float* __restrict__ beta, float* __restrict__ out) {
  int t = blockIdx.y;
  int wave = threadIdx.x >> 6;
  int lane = threadIdx.x & 63;
  int b0 = blockIdx.x * 8 + wave;
  int b1 = b0 + 4;

  float gva = g_in[((size_t)b0 * T_N + t) * K_TOP + lane];
  float gvb = g_in[((size_t)b1 * T_N + t) * K_TOP + lane];

  const float* wt = Wd + (size_t)t * K_TOP * O_N;
  const float* bdt = bd + t * O_N;
  float a0 = bdt[lane], a1 = bdt[64 + lane], a2 = bdt[128 + lane], a3 = bdt[192 + lane];
  float c0 = a0, c1 = a1, c2 = a2, c3 = a3;
#pragma unroll
  for (int k = 0; k < K_TOP; k++) {
    const float* wr = wt + k * O_N + lane;
    float w0 = wr[0], w1 = wr[64], w2 = wr[128], w3 = wr[192];
    float ga = __shfl(gva, k); // literal k -> v_readlane broadcast
    float gb = __shfl(gvb, k);
    a0 = fmaf(ga, w0, a0); a1 = fmaf(ga, w1, a1);
    a2 = fmaf(ga, w2, a2); a3 = fmaf(ga, w3, a3);
    c0 = fmaf(gb, w0, c0); c1 = fmaf(gb, w1, c1);
    c2 = fmaf(gb, w2, c2); c3 = fmaf(gb, w3, c3);
  }
  const float* gm = gamma + t * O_N;
  const float* bt = beta + t * O_N;
  gelu_ln_store(a0, a1, a2, a3, gm, bt, out + ((size_t)b0 * T_N + t) * O_N, lane);
  gelu_ln_store(c0, c1, c2, c3, gm, bt, out + ((size_t)b1 * T_N + t) * O_N, lane);
}

// ---------------- launch ----------------
extern "C" void kernel_launch(void* const* d_in, const int* in_sizes, int n_in,
                              void* d_out, int out_size, void* d_ws, size_t ws_size,
                              hipStream_t stream) {
  const float* x = (const float*)d_in[0];
  const float* Wt = (const float*)d_in[1];
  const float* Wd = (const float*)d_in[2];
  const float* bd = (const float*)d_in[3];
  const float* gamma = (const float*)d_in[4];
  const float* beta = (const float*)d_in[5];
  float* out = (float*)d_out;

  char* ws = (char*)d_ws;
  size_t sz_wt = (size_t)T_N * H_N * L_N * 2; // 128 MB
  size_t sz_x = (size_t)B_N * L_N * 2;        // 2 MB
  size_t off_h = sz_wt + sz_x;
  size_t sz_h_f32 = (size_t)B_N * NCOL * 4;   // 256 MB
  size_t sz_h_b16 = (size_t)B_N * NCOL * 2;   // 128 MB
  size_t sz_g = (size_t)B_N * T_N * K_TOP * 4; // 8 MB

  bf16_t* WTb = (bf16_t*)ws;
  bf16_t* Xb = (bf16_t*)(ws + sz_wt);

  cvt_x_kernel<<<B_N * L_N / 1024, 256, 0, stream>>>(x, Xb);
  cvt_w_kernel<<<dim3(H_N / 64, L_N / 64, T_N), 256, 0, stream>>>(Wt, WTb);

  if (ws_size >= off_h + sz_h_f32) {
    float* hidden = (float*)(ws + off_h);
    // g buffer: after hidden if it fits, else overlap WT (dead after gemm1)
    float* gbuf = (ws_size >= off_h + sz_h_f32 + sz_g)
                      ? (float*)(ws + off_h + sz_h_f32)
                      : (float*)ws;
    gemm1_kernel<float><<<4096, 256, 0, stream>>>(Xb, WTb, hidden);
    topk_select_kernel<float><<<dim3(B_N / 4, T_N), 256, 0, stream>>>(hidden, gbuf);
    dense_tail_kernel<<<dim3(B_N / 8, T_N), 256, 0, stream>>>(gbuf, Wd, bd, gamma,
                                                              beta, out);
  } else { // fall back to bf16 hidden (270 MB total ws)
    bf16_t* hidden = (bf16_t*)(ws + off_h);
    float* gbuf = (ws_size >= off_h + sz_h_b16 + sz_g)
                      ? (float*)(ws + off_h + sz_h_b16)
                      : (float*)ws;
    gemm1_kernel<bf16_t><<<4096, 256, 0, stream>>>(Xb, WTb, hidden);
    topk_select_kernel<bf16_t><<<dim3(B_N / 4, T_N), 256, 0, stream>>>(hidden, gbuf);
    dense_tail_kernel<<<dim3(B_N / 8, T_N), 256, 0, stream>>>(gbuf, Wd, bd, gamma,
                                                              beta, out);
  }
}

// Round 2
// 2087.710 us; speedup vs baseline: 1.0891x; 1.0891x over previous
//
#include <hip/hip_runtime.h>
#include <hip/hip_bf16.h>
#include <math.h>

typedef __bf16 bf16_t;
typedef __bf16 bf16x2_t __attribute__((ext_vector_type(2)));
typedef __bf16 bf16x4_t __attribute__((ext_vector_type(4)));
typedef __bf16 bf16x8_t __attribute__((ext_vector_type(8)));
typedef float f32x4_t __attribute__((ext_vector_type(4)));

#define B_N 1024
#define L_N 1024
#define T_N 32
#define H_N 2048
#define K_TOP 64
#define O_N 256
#define NCOL (T_N * H_N) /* 65536 */

// VGPR-budget rule on gfx950 (verified R1 post-mortems, two sessions):
//   __launch_bounds__(256, w) caps VGPRs at 256/w.
//   (256,2)->128ok  (256,4)->64  (256,6)->42 SPILLED select  (256,8)->32 SPILLED dense (5GB scratch)

// ---------------- conversion: x -> bf16 ----------------
__global__ __launch_bounds__(256) void cvt_x_kernel(const float* __restrict__ x,
                                                    bf16_t* __restrict__ xb) {
  int i = (blockIdx.x * 256 + threadIdx.x) * 4;
  float4 v = *(const float4*)(x + i);
  bf16x4_t o;
  o[0] = (bf16_t)v.x; o[1] = (bf16_t)v.y; o[2] = (bf16_t)v.z; o[3] = (bf16_t)v.w;
  *(bf16x4_t*)(xb + i) = o;
}

// -------- conversion+transpose: Wt [T,L,H] f32 -> WT [T,H,L] bf16 --------
__global__ __launch_bounds__(256) void cvt_w_kernel(const float* __restrict__ W,
                                                    bf16_t* __restrict__ WT) {
  __shared__ float tile[64][65];
  int t = blockIdx.z;
  int h0 = blockIdx.x * 64;
  int l0 = blockIdx.y * 64;
  const float* src = W + (size_t)t * L_N * H_N;
  int hx = threadIdx.x & 63;
  int ly = threadIdx.x >> 6;
#pragma unroll
  for (int r = 0; r < 64; r += 4)
    tile[ly + r][hx] = src[(size_t)(l0 + ly + r) * H_N + h0 + hx];
  __syncthreads();
  bf16_t* dst = WT + (size_t)t * H_N * L_N;
  int lx = (threadIdx.x & 31) * 2;
  int hy = threadIdx.x >> 5;
#pragma unroll
  for (int r = 0; r < 64; r += 8) {
    int h = hy + r;
    bf16x2_t o;
    o[0] = (bf16_t)tile[lx][h];
    o[1] = (bf16_t)tile[lx + 1][h];
    *(bf16x2_t*)(dst + (size_t)(h0 + h) * L_N + l0 + lx) = o;
  }
}

// ---------------- GEMM1: hidden[b, t*2048+h] = sum_l x[b,l]*W[t,l,h] ----------------
#define BM 128
#define BN 128
#define BK 32

__device__ __forceinline__ void async_load16(const void* g, void* l) {
  __builtin_amdgcn_global_load_lds((const __attribute__((address_space(1))) void*)g,
                                   (__attribute__((address_space(3))) void*)l,
                                   16, 0, 0);
}

template <typename HT>
__global__ __launch_bounds__(256) void gemm1_kernel(const bf16_t* __restrict__ Xb,
                                                    const bf16_t* __restrict__ WT,
                                                    HT* __restrict__ hidden) {
  __shared__ bf16_t As[BM][BK]; // [m][k], row = 64 B
  __shared__ bf16_t Bs[BN][BK]; // [n][k], row = 64 B  (WT is already [n][k] in global)
  int tid = threadIdx.x;
  int wave = tid >> 6;
  int lane = tid & 63;
  int bid = blockIdx.x;
  int m0 = (bid & 7) * BM;      // 8 row tiles over B=1024
  int nbase = (bid >> 3) * BN;  // 512 col tiles over T*H=65536

  const bf16_t* Aptr = Xb + (size_t)m0 * L_N;
  const bf16_t* Bptr = WT + (size_t)nbase * L_N;

  // staging: lane i copies 16 B; wave covers 16 contiguous 64 B LDS rows
  int srow = lane >> 2;
  int scol = lane & 3;
  size_t soff = (size_t)(wave * 16 + srow) * L_N + scol * 8;

  f32x4_t acc[4][4];
  f32x4_t zero = {0.f, 0.f, 0.f, 0.f};
#pragma unroll
  for (int i = 0; i < 4; i++)
#pragma unroll
    for (int j = 0; j < 4; j++) acc[i][j] = zero;

  int wm = wave >> 1, wn = wave & 1;
  int fr = lane & 15;
  int fq = lane >> 4;

  for (int k0 = 0; k0 < L_N; k0 += BK) {
    const bf16_t* ga = Aptr + soff + k0;
    const bf16_t* gb = Bptr + soff + k0;
    async_load16(ga, &As[wave * 16][0]);
    async_load16(ga + 64 * L_N, &As[64 + wave * 16][0]);
    async_load16(gb, &Bs[wave * 16][0]);
    async_load16(gb + 64 * L_N, &Bs[64 + wave * 16][0]);
    __syncthreads();
    bf16x8_t af[4], bfv[4];
#pragma unroll
    for (int i = 0; i < 4; i++)
      af[i] = *(const bf16x8_t*)&As[wm * 64 + i * 16 + fr][fq * 8];
#pragma unroll
    for (int j = 0; j < 4; j++)
      bfv[j] = *(const bf16x8_t*)&Bs[wn * 64 + j * 16 + fr][fq * 8];
#pragma unroll
    for (int i = 0; i < 4; i++)
#pragma unroll
      for (int j = 0; j < 4; j++)
        acc[i][j] = __builtin_amdgcn_mfma_f32_16x16x32_bf16(af[i], bfv[j], acc[i][j], 0, 0, 0);
    __syncthreads();
  }

  // C/D layout: col = lane&15, row = (lane>>4)*4 + r  [verified m89/m91]
#pragma unroll
  for (int i = 0; i < 4; i++) {
    int gm = m0 + wm * 64 + i * 16 + fq * 4;
#pragma unroll
    for (int j = 0; j < 4; j++) {
      int gn = nbase + wn * 64 + j * 16 + fr;
      HT* outp = hidden + (size_t)gm * NCOL + gn;
#pragma unroll
      for (int r = 0; r < 4; r++) outp[(size_t)r * NCOL] = (HT)acc[i][j][r];
    }
  }
}

// ---------------- helpers shared by the tail kernels ----------------

__device__ __forceinline__ float wave_reduce_sum(float v) {
#pragma unroll
  for (int off = 32; off > 0; off >>= 1) v += __shfl_xor(v, off);
  return v;
}

// order-preserving float->uint key and inverse
__device__ __forceinline__ unsigned f2key(float f) {
  unsigned u = __float_as_uint(f);
  return u ^ ((u >> 31) ? 0xFFFFFFFFu : 0x80000000u);
}
__device__ __forceinline__ float key2f(unsigned k) {
  return __uint_as_float(k ^ ((k >> 31) ? 0x80000000u : 0xFFFFFFFFu));
}

__device__ __forceinline__ int lanes_below(unsigned long long m) {
  return (int)__builtin_amdgcn_mbcnt_hi((unsigned)(m >> 32),
                                        __builtin_amdgcn_mbcnt_lo((unsigned)m, 0u));
}

// f32 path: 2 batches of 4x16B loads — staging peak 16 VGPRs on top of key[32]
__device__ __forceinline__ void load_keys(const float* __restrict__ row, int lane,
                                          unsigned key[32]) {
  const float4* r4 = (const float4*)row;
#pragma unroll
  for (int h = 0; h < 2; h++) {
    float4 v[4];
#pragma unroll
    for (int q = 0; q < 4; q++) v[q] = r4[lane + 64 * (h * 4 + q)];
#pragma unroll
    for (int q = 0; q < 4; q++) {
      int o = (h * 4 + q) * 4;
      key[o + 0] = f2key(v[q].x);
      key[o + 1] = f2key(v[q].y);
      key[o + 2] = f2key(v[q].z);
      key[o + 3] = f2key(v[q].w);
    }
  }
}

__device__ __forceinline__ void load_keys(const bf16_t* __restrict__ row, int lane,
                                          unsigned key[32]) {
  const bf16x8_t* r8 = (const bf16x8_t*)row;
#pragma unroll
  for (int h = 0; h < 2; h++) {
    bf16x8_t v[2];
#pragma unroll
    for (int q = 0; q < 2; q++) v[q] = r8[lane + 64 * (h * 2 + q)];
#pragma unroll
    for (int q = 0; q < 2; q++)
#pragma unroll
      for (int j = 0; j < 8; j++) key[(h * 2 + q) * 8 + j] = f2key((float)v[q][j]);
  }
}

// ---------------- kernel A: top-64 select + sort -> g[B,T,64] f32 ----------------
// (256,3) = 85-VGPR budget; measured need ~60 (key 32 + staging 16 + temps ~12).
// (256,6)=42 budget spilled key[] to scratch in R1 — never go below need.
template <typename HT>
__global__ __launch_bounds__(256, 3) void topk_select_kernel(
    const HT* __restrict__ hidden, float* __restrict__ g_out) {
  __shared__ unsigned slots[4][K_TOP];
  int t = blockIdx.y;
  int wave = threadIdx.x >> 6;
  int lane = threadIdx.x & 63;
  int b = blockIdx.x * 4 + wave;

  unsigned key[32];
  load_keys(hidden + (size_t)b * NCOL + (size_t)t * H_N, lane, key);

  // exact 64th-largest key: largest thr with count(key >= thr) >= 64
  unsigned thr = 0;
  for (int bit = 31; bit >= 0; --bit) {
    unsigned cand = thr | (1u << bit);
    int c = 0;
#pragma unroll
    for (int i = 0; i < 32; i++) c += (int)__popcll(__ballot(key[i] >= cand));
    if (c >= K_TOP) thr = cand; // wave-uniform
  }

  // compaction via ballot prefix (no atomics, wave-local LDS only)
  int base = 0;
#pragma unroll
  for (int i = 0; i < 32; i++) {
    bool p = key[i] > thr;
    unsigned long long m = __ballot(p);
    if (p) slots[wave][base + lanes_below(m)] = key[i];
    base += (int)__popcll(m);
  }
#pragma unroll
  for (int i = 0; i < 32; i++) {
    bool p = key[i] == thr;
    unsigned long long m = __ballot(p);
    if (p) {
      int pos = base + lanes_below(m);
      if (pos < K_TOP) slots[wave][pos] = key[i];
    }
    base += (int)__popcll(m);
  }

  // 64-lane register bitonic sort, descending (unsigned keys)
  unsigned g = slots[wave][lane];
#pragma unroll
  for (int k = 2; k <= 64; k <<= 1) {
#pragma unroll
    for (int j = k >> 1; j > 0; j >>= 1) {
      unsigned other = (unsigned)__shfl_xor((int)g, j);
      bool keep_max = (((lane & k) == 0) != ((lane & j) != 0));
      unsigned mx = g > other ? g : other;
      unsigned mn = g > other ? other : g;
      g = keep_max ? mx : mn;
    }
  }
  g_out[((size_t)b * T_N + t) * K_TOP + lane] = key2f(g);
}

// ---------------- kernel B: dense + GELU + LN from g ----------------

__device__ __forceinline__ void gelu_ln_store(float y0, float y1, float y2, float y3,
                                              const float* __restrict__ gm,
                                              const float* __restrict__ bt,
                                              float* __restrict__ op, int lane) {
  const float is2 = 0.70710678118654752f;
  y0 = 0.5f * y0 * (1.f + erff(y0 * is2));
  y1 = 0.5f * y1 * (1.f + erff(y1 * is2));
  y2 = 0.5f * y2 * (1.f + erff(y2 * is2));
  y3 = 0.5f * y3 * (1.f + erff(y3 * is2));
  float mean = wave_reduce_sum(y0 + y1 + y2 + y3) * (1.f / 256.f);
  float d0 = y0 - mean, d1 = y1 - mean, d2 = y2 - mean, d3 = y3 - mean;
  float var = wave_reduce_sum(d0 * d0 + d1 * d1 + d2 * d2 + d3 * d3) * (1.f / 256.f);
  float rstd = rsqrtf(var + 1e-6f);
  op[lane] = d0 * rstd * gm[lane] + bt[lane];
  op[64 + lane] = d1 * rstd * gm[64 + lane] + bt[64 + lane];
  op[128 + lane] = d2 * rstd * gm[128 + lane] + bt[128 + lane];
  op[192 + lane] = d3 * rstd * gm[192 + lane] + bt[192 + lane];
}

// (256,4) = 64-VGPR budget; need ~40 (acc 16 + gv 4 + w 4 + addr/temps).
// 4 rows/wave: each 1 KB Wd row from L2 feeds 16 FMAs (halves L2 traffic vs 2).
__global__ __launch_bounds__(256, 4) void dense_tail_kernel(
    const float* __restrict__ g_in, const float* __restrict__ Wd,
    const float* __restrict__ bd, const float* __restrict__ gamma,
    const float* __restrict__ beta, float* __restrict__ out) {
  int t = blockIdx.y;
  int wave = threadIdx.x >> 6;
  int lane = threadIdx.x & 63;
  int b0 = blockIdx.x * 16 + wave; // rows b0, b0+4, b0+8, b0+12

  float gv0 = g_in[((size_t)(b0)*T_N + t) * K_TOP + lane];
  float gv1 = g_in[((size_t)(b0 + 4) * T_N + t) * K_TOP + lane];
  float gv2 = g_in[((size_t)(b0 + 8) * T_N + t) * K_TOP + lane];
  float gv3 = g_in[((size_t)(b0 + 12) * T_N + t) * K_TOP + lane];

  const float* wt = Wd + (size_t)t * K_TOP * O_N;
  const float* bdt = bd + t * O_N;
  float bb0 = bdt[lane], bb1 = bdt[64 + lane], bb2 = bdt[128 + lane], bb3 = bdt[192 + lane];
  float a0 = bb0, a1 = bb1, a2 = bb2, a3 = bb3;
  float c0 = bb0, c1 = bb1, c2 = bb2, c3 = bb3;
  float e0 = bb0, e1 = bb1, e2 = bb2, e3 = bb3;
  float f0 = bb0, f1 = bb1, f2 = bb2, f3 = bb3;
#pragma unroll
  for (int k = 0; k < K_TOP; k++) {
    const float* wr = wt + k * O_N + lane;
    float w0 = wr[0], w1 = wr[64], w2 = wr[128], w3 = wr[192];
    float ga = __shfl(gv0, k); // literal k -> v_readlane broadcast
    float gb = __shfl(gv1, k);
    float gc = __shfl(gv2, k);
    float gd = __shfl(gv3, k);
    a0 = fmaf(ga, w0, a0); a1 = fmaf(ga, w1, a1);
    a2 = fmaf(ga, w2, a2); a3 = fmaf(ga, w3, a3);
    c0 = fmaf(gb, w0, c0); c1 = fmaf(gb, w1, c1);
    c2 = fmaf(gb, w2, c2); c3 = fmaf(gb, w3, c3);
    e0 = fmaf(gc, w0, e0); e1 = fmaf(gc, w1, e1);
    e2 = fmaf(gc, w2, e2); e3 = fmaf(gc, w3, e3);
    f0 = fmaf(gd, w0, f0); f1 = fmaf(gd, w1, f1);
    f2 = fmaf(gd, w2, f2); f3 = fmaf(gd, w3, f3);
  }
  const float* gm = gamma + t * O_N;
  const float* bt = beta + t * O_N;
  gelu_ln_store(a0, a1, a2, a3, gm, bt, out + ((size_t)(b0)*T_N + t) * O_N, lane);
  gelu_ln_store(c0, c1, c2, c3, gm, bt, out + ((size_t)(b0 + 4) * T_N + t) * O_N, lane);
  gelu_ln_store(e0, e1, e2, e3, gm, bt, out + ((size_t)(b0 + 8) * T_N + t) * O_N, lane);
  gelu_ln_store(f0, f1, f2, f3, gm, bt, out + ((size_t)(b0 + 12) * T_N + t) * O_N, lane);
}

// ---------------- launch ----------------
extern "C" void kernel_launch(void* const* d_in, const int* in_sizes, int n_in,
                              void* d_out, int out_size, void* d_ws, size_t ws_size,
                              hipStream_t stream) {
  const float* x = (const float*)d_in[0];
  const float* Wt = (const float*)d_in[1];
  const float* Wd = (const float*)d_in[2];
  const float* bd = (const float*)d_in[3];
  const float* gamma = (const float*)d_in[4];
  const float* beta = (const float*)d_in[5];
  float* out = (float*)d_out;

  char* ws = (char*)d_ws;
  size_t sz_wt = (size_t)T_N * H_N * L_N * 2; // 128 MB
  size_t sz_x = (size_t)B_N * L_N * 2;        // 2 MB
  size_t off_h = sz_wt + sz_x;
  size_t sz_h_f32 = (size_t)B_N * NCOL * 4;   // 256 MB
  size_t sz_h_b16 = (size_t)B_N * NCOL * 2;   // 128 MB
  size_t sz_g = (size_t)B_N * T_N * K_TOP * 4; // 8 MB

  bf16_t* WTb = (bf16_t*)ws;
  bf16_t* Xb = (bf16_t*)(ws + sz_wt);

  cvt_x_kernel<<<B_N * L_N / 1024, 256, 0, stream>>>(x, Xb);
  cvt_w_kernel<<<dim3(H_N / 64, L_N / 64, T_N), 256, 0, stream>>>(Wt, WTb);

  if (ws_size >= off_h + sz_h_f32) {
    float* hidden = (float*)(ws + off_h);
    // g buffer: after hidden if it fits, else overlap WT (dead after gemm1)
    float* gbuf = (ws_size >= off_h + sz_h_f32 + sz_g)
                      ? (float*)(ws + off_h + sz_h_f32)
                      : (float*)ws;
    gemm1_kernel<float><<<4096, 256, 0, stream>>>(Xb, WTb, hidden);
    topk_select_kernel<float><<<dim3(B_N / 4, T_N), 256, 0, stream>>>(hidden, gbuf);
    dense_tail_kernel<<<dim3(B_N / 16, T_N), 256, 0, stream>>>(gbuf, Wd, bd, gamma,
                                                               beta, out);
  } else { // fall back to bf16 hidden (270 MB total ws)
    bf16_t* hidden = (bf16_t*)(ws + off_h);
    float* gbuf = (ws_size >= off_h + sz_h_b16 + sz_g)
                      ? (float*)(ws + off_h + sz_h_b16)
                      : (float*)ws;
    gemm1_kernel<bf16_t><<<4096, 256, 0, stream>>>(Xb, WTb, hidden);
    topk_select_kernel<bf16_t><<<dim3(B_N / 4, T_N), 256, 0, stream>>>(hidden, gbuf);
    dense_tail_kernel<<<dim3(B_N / 16, T_N), 256, 0, stream>>>(gbuf, Wd, bd, gamma,
                                                               beta, out);
  }
}

// Round 3
// 1809.196 us; speedup vs baseline: 1.2568x; 1.1539x over previous
//
#include <hip/hip_runtime.h>
#include <hip/hip_bf16.h>
#include <math.h>

typedef __bf16 bf16_t;
typedef __bf16 bf16x2_t __attribute__((ext_vector_type(2)));
typedef __bf16 bf16x4_t __attribute__((ext_vector_type(4)));
typedef __bf16 bf16x8_t __attribute__((ext_vector_type(8)));
typedef float f32x4_t __attribute__((ext_vector_type(4)));

#define B_N 1024
#define L_N 1024
#define T_N 32
#define H_N 2048
#define K_TOP 64
#define O_N 256
#define NCOL (T_N * H_N) /* 65536 */

// VGPR-budget rule on gfx950 (verified R1/R2 post-mortems):
//   __launch_bounds__(256, w) caps VGPRs at 256/w.
//   Register need under full unroll = persistent regs + compiler's VMEM
//   load-batch window (~16-32). dense_tail spilled at BOTH 32 and 64 caps
//   because of the load window -> fix is LDS-staging Wd, not cap tuning.

// ---------------- conversion: x -> bf16 ----------------
__global__ __launch_bounds__(256) void cvt_x_kernel(const float* __restrict__ x,
                                                    bf16_t* __restrict__ xb) {
  int i = (blockIdx.x * 256 + threadIdx.x) * 4;
  float4 v = *(const float4*)(x + i);
  bf16x4_t o;
  o[0] = (bf16_t)v.x; o[1] = (bf16_t)v.y; o[2] = (bf16_t)v.z; o[3] = (bf16_t)v.w;
  *(bf16x4_t*)(xb + i) = o;
}

// -------- conversion+transpose: Wt [T,L,H] f32 -> WT [T,H,L] bf16 --------
__global__ __launch_bounds__(256) void cvt_w_kernel(const float* __restrict__ W,
                                                    bf16_t* __restrict__ WT) {
  __shared__ float tile[64][65];
  int t = blockIdx.z;
  int h0 = blockIdx.x * 64;
  int l0 = blockIdx.y * 64;
  const float* src = W + (size_t)t * L_N * H_N;
  int hx = threadIdx.x & 63;
  int ly = threadIdx.x >> 6;
#pragma unroll
  for (int r = 0; r < 64; r += 4)
    tile[ly + r][hx] = src[(size_t)(l0 + ly + r) * H_N + h0 + hx];
  __syncthreads();
  bf16_t* dst = WT + (size_t)t * H_N * L_N;
  int lx = (threadIdx.x & 31) * 2;
  int hy = threadIdx.x >> 5;
#pragma unroll
  for (int r = 0; r < 64; r += 8) {
    int h = hy + r;
    bf16x2_t o;
    o[0] = (bf16_t)tile[lx][h];
    o[1] = (bf16_t)tile[lx + 1][h];
    *(bf16x2_t*)(dst + (size_t)(h0 + h) * L_N + l0 + lx) = o;
  }
}

// ---------------- GEMM1: hidden[b, t*2048+h] = sum_l x[b,l]*W[t,l,h] ----------------
#define BM 128
#define BN 128
#define BK 32

__device__ __forceinline__ void async_load16(const void* g, void* l) {
  __builtin_amdgcn_global_load_lds((const __attribute__((address_space(1))) void*)g,
                                   (__attribute__((address_space(3))) void*)l,
                                   16, 0, 0);
}

template <typename HT>
__global__ __launch_bounds__(256) void gemm1_kernel(const bf16_t* __restrict__ Xb,
                                                    const bf16_t* __restrict__ WT,
                                                    HT* __restrict__ hidden) {
  __shared__ bf16_t As[BM][BK]; // [m][k], row = 64 B
  __shared__ bf16_t Bs[BN][BK]; // [n][k], row = 64 B  (WT is already [n][k] in global)
  int tid = threadIdx.x;
  int wave = tid >> 6;
  int lane = tid & 63;
  int bid = blockIdx.x;
  int m0 = (bid & 7) * BM;      // 8 row tiles over B=1024
  int nbase = (bid >> 3) * BN;  // 512 col tiles over T*H=65536

  const bf16_t* Aptr = Xb + (size_t)m0 * L_N;
  const bf16_t* Bptr = WT + (size_t)nbase * L_N;

  // staging: lane i copies 16 B; wave covers 16 contiguous 64 B LDS rows
  int srow = lane >> 2;
  int scol = lane & 3;
  size_t soff = (size_t)(wave * 16 + srow) * L_N + scol * 8;

  f32x4_t acc[4][4];
  f32x4_t zero = {0.f, 0.f, 0.f, 0.f};
#pragma unroll
  for (int i = 0; i < 4; i++)
#pragma unroll
    for (int j = 0; j < 4; j++) acc[i][j] = zero;

  int wm = wave >> 1, wn = wave & 1;
  int fr = lane & 15;
  int fq = lane >> 4;

  for (int k0 = 0; k0 < L_N; k0 += BK) {
    const bf16_t* ga = Aptr + soff + k0;
    const bf16_t* gb = Bptr + soff + k0;
    async_load16(ga, &As[wave * 16][0]);
    async_load16(ga + 64 * L_N, &As[64 + wave * 16][0]);
    async_load16(gb, &Bs[wave * 16][0]);
    async_load16(gb + 64 * L_N, &Bs[64 + wave * 16][0]);
    __syncthreads();
    bf16x8_t af[4], bfv[4];
#pragma unroll
    for (int i = 0; i < 4; i++)
      af[i] = *(const bf16x8_t*)&As[wm * 64 + i * 16 + fr][fq * 8];
#pragma unroll
    for (int j = 0; j < 4; j++)
      bfv[j] = *(const bf16x8_t*)&Bs[wn * 64 + j * 16 + fr][fq * 8];
#pragma unroll
    for (int i = 0; i < 4; i++)
#pragma unroll
      for (int j = 0; j < 4; j++)
        acc[i][j] = __builtin_amdgcn_mfma_f32_16x16x32_bf16(af[i], bfv[j], acc[i][j], 0, 0, 0);
    __syncthreads();
  }

  // C/D layout: col = lane&15, row = (lane>>4)*4 + r  [verified m89/m91]
#pragma unroll
  for (int i = 0; i < 4; i++) {
    int gm = m0 + wm * 64 + i * 16 + fq * 4;
#pragma unroll
    for (int j = 0; j < 4; j++) {
      int gn = nbase + wn * 64 + j * 16 + fr;
      HT* outp = hidden + (size_t)gm * NCOL + gn;
#pragma unroll
      for (int r = 0; r < 4; r++) outp[(size_t)r * NCOL] = (HT)acc[i][j][r];
    }
  }
}

// ---------------- helpers shared by the tail kernels ----------------

__device__ __forceinline__ float wave_reduce_sum(float v) {
#pragma unroll
  for (int off = 32; off > 0; off >>= 1) v += __shfl_xor(v, off);
  return v;
}

// order-preserving float->uint key and inverse
__device__ __forceinline__ unsigned f2key(float f) {
  unsigned u = __float_as_uint(f);
  return u ^ ((u >> 31) ? 0xFFFFFFFFu : 0x80000000u);
}
__device__ __forceinline__ float key2f(unsigned k) {
  return __uint_as_float(k ^ ((k >> 31) ? 0x80000000u : 0xFFFFFFFFu));
}

__device__ __forceinline__ int lanes_below(unsigned long long m) {
  return (int)__builtin_amdgcn_mbcnt_hi((unsigned)(m >> 32),
                                        __builtin_amdgcn_mbcnt_lo((unsigned)m, 0u));
}

// f32 path: 2 batches of 4x16B loads — staging peak 16 VGPRs on top of key[32]
__device__ __forceinline__ void load_keys(const float* __restrict__ row, int lane,
                                          unsigned key[32]) {
  const float4* r4 = (const float4*)row;
#pragma unroll
  for (int h = 0; h < 2; h++) {
    float4 v[4];
#pragma unroll
    for (int q = 0; q < 4; q++) v[q] = r4[lane + 64 * (h * 4 + q)];
#pragma unroll
    for (int q = 0; q < 4; q++) {
      int o = (h * 4 + q) * 4;
      key[o + 0] = f2key(v[q].x);
      key[o + 1] = f2key(v[q].y);
      key[o + 2] = f2key(v[q].z);
      key[o + 3] = f2key(v[q].w);
    }
  }
}

__device__ __forceinline__ void load_keys(const bf16_t* __restrict__ row, int lane,
                                          unsigned key[32]) {
  const bf16x8_t* r8 = (const bf16x8_t*)row;
#pragma unroll
  for (int h = 0; h < 2; h++) {
    bf16x8_t v[2];
#pragma unroll
    for (int q = 0; q < 2; q++) v[q] = r8[lane + 64 * (h * 2 + q)];
#pragma unroll
    for (int q = 0; q < 2; q++)
#pragma unroll
      for (int j = 0; j < 8; j++) key[(h * 2 + q) * 8 + j] = f2key((float)v[q][j]);
  }
}

// ---------------- kernel A: top-64 select + sort -> g[B,T,64] f32 ----------------
// (256,3) = 85-VGPR budget; measured need ~60 (key 32 + staging 16 + temps ~12).
template <typename HT>
__global__ __launch_bounds__(256, 3) void topk_select_kernel(
    const HT* __restrict__ hidden, float* __restrict__ g_out) {
  __shared__ unsigned slots[4][K_TOP];
  int t = blockIdx.y;
  int wave = threadIdx.x >> 6;
  int lane = threadIdx.x & 63;
  int b = blockIdx.x * 4 + wave;

  unsigned key[32];
  load_keys(hidden + (size_t)b * NCOL + (size_t)t * H_N, lane, key);

  // exact 64th-largest key: largest thr with count(key >= thr) >= 64
  unsigned thr = 0;
  for (int bit = 31; bit >= 0; --bit) {
    unsigned cand = thr | (1u << bit);
    int c = 0;
#pragma unroll
    for (int i = 0; i < 32; i++) c += (int)__popcll(__ballot(key[i] >= cand));
    if (c >= K_TOP) thr = cand; // wave-uniform
  }

  // compaction via ballot prefix (no atomics, wave-local LDS only)
  int base = 0;
#pragma unroll
  for (int i = 0; i < 32; i++) {
    bool p = key[i] > thr;
    unsigned long long m = __ballot(p);
    if (p) slots[wave][base + lanes_below(m)] = key[i];
    base += (int)__popcll(m);
  }
#pragma unroll
  for (int i = 0; i < 32; i++) {
    bool p = key[i] == thr;
    unsigned long long m = __ballot(p);
    if (p) {
      int pos = base + lanes_below(m);
      if (pos < K_TOP) slots[wave][pos] = key[i];
    }
    base += (int)__popcll(m);
  }

  // 64-lane register bitonic sort, descending (unsigned keys)
  unsigned g = slots[wave][lane];
#pragma unroll
  for (int k = 2; k <= 64; k <<= 1) {
#pragma unroll
    for (int j = k >> 1; j > 0; j >>= 1) {
      unsigned other = (unsigned)__shfl_xor((int)g, j);
      bool keep_max = (((lane & k) == 0) != ((lane & j) != 0));
      unsigned mx = g > other ? g : other;
      unsigned mn = g > other ? other : g;
      g = keep_max ? mx : mn;
    }
  }
  g_out[((size_t)b * T_N + t) * K_TOP + lane] = key2f(g);
}

// ---------------- kernel B: dense + GELU + LN from g ----------------

__device__ __forceinline__ void gelu_ln_store(float y0, float y1, float y2, float y3,
                                              const float* __restrict__ gm,
                                              const float* __restrict__ bt,
                                              float* __restrict__ op, int lane) {
  const float is2 = 0.70710678118654752f;
  y0 = 0.5f * y0 * (1.f + erff(y0 * is2));
  y1 = 0.5f * y1 * (1.f + erff(y1 * is2));
  y2 = 0.5f * y2 * (1.f + erff(y2 * is2));
  y3 = 0.5f * y3 * (1.f + erff(y3 * is2));
  float mean = wave_reduce_sum(y0 + y1 + y2 + y3) * (1.f / 256.f);
  float d0 = y0 - mean, d1 = y1 - mean, d2 = y2 - mean, d3 = y3 - mean;
  float var = wave_reduce_sum(d0 * d0 + d1 * d1 + d2 * d2 + d3 * d3) * (1.f / 256.f);
  float rstd = rsqrtf(var + 1e-6f);
  op[lane] = d0 * rstd * gm[lane] + bt[lane];
  op[64 + lane] = d1 * rstd * gm[64 + lane] + bt[64 + lane];
  op[128 + lane] = d2 * rstd * gm[128 + lane] + bt[128 + lane];
  op[192 + lane] = d3 * rstd * gm[192 + lane] + bt[192 + lane];
}

// Wd tile for one t = 64x256 f32 = 64 KB -> LDS, loaded once per block.
// k-loop operands come from ds_read (short latency, no VMEM batch window)
// -> spill mechanism gone. (256,2)=128-VGPR budget; LDS caps 2 blocks/CU
// (= 2 waves/SIMD) which is plenty for an L2/LDS-fed FMA loop with 16-way ILP.
__global__ __launch_bounds__(256, 2) void dense_tail_kernel(
    const float* __restrict__ g_in, const float* __restrict__ Wd,
    const float* __restrict__ bd, const float* __restrict__ gamma,
    const float* __restrict__ beta, float* __restrict__ out) {
  __shared__ float wlds[K_TOP * O_N]; // 64 KB
  int t = blockIdx.y;
  int wave = threadIdx.x >> 6;
  int lane = threadIdx.x & 63;
  int b0 = blockIdx.x * 16 + wave; // rows b0, b0+4, b0+8, b0+12

  // cooperative Wd stage: 16384 floats = 4096 float4, 16 per thread
  {
    const float4* src = (const float4*)(Wd + (size_t)t * K_TOP * O_N);
    float4* dstl = (float4*)wlds;
#pragma unroll
    for (int i = 0; i < 16; i++) dstl[threadIdx.x + 256 * i] = src[threadIdx.x + 256 * i];
  }

  float gv0 = g_in[((size_t)(b0)*T_N + t) * K_TOP + lane];
  float gv1 = g_in[((size_t)(b0 + 4) * T_N + t) * K_TOP + lane];
  float gv2 = g_in[((size_t)(b0 + 8) * T_N + t) * K_TOP + lane];
  float gv3 = g_in[((size_t)(b0 + 12) * T_N + t) * K_TOP + lane];

  const float* bdt = bd + t * O_N;
  float bb0 = bdt[lane], bb1 = bdt[64 + lane], bb2 = bdt[128 + lane], bb3 = bdt[192 + lane];
  float a0 = bb0, a1 = bb1, a2 = bb2, a3 = bb3;
  float c0 = bb0, c1 = bb1, c2 = bb2, c3 = bb3;
  float e0 = bb0, e1 = bb1, e2 = bb2, e3 = bb3;
  float f0 = bb0, f1 = bb1, f2 = bb2, f3 = bb3;

  __syncthreads();
#pragma unroll
  for (int k = 0; k < K_TOP; k++) {
    const float* wr = wlds + k * O_N + lane; // stride-1 across lanes: conflict-free
    float w0 = wr[0], w1 = wr[64], w2 = wr[128], w3 = wr[192];
    float ga = __shfl(gv0, k); // literal k -> v_readlane broadcast
    float gb = __shfl(gv1, k);
    float gc = __shfl(gv2, k);
    float gd = __shfl(gv3, k);
    a0 = fmaf(ga, w0, a0); a1 = fmaf(ga, w1, a1);
    a2 = fmaf(ga, w2, a2); a3 = fmaf(ga, w3, a3);
    c0 = fmaf(gb, w0, c0); c1 = fmaf(gb, w1, c1);
    c2 = fmaf(gb, w2, c2); c3 = fmaf(gb, w3, c3);
    e0 = fmaf(gc, w0, e0); e1 = fmaf(gc, w1, e1);
    e2 = fmaf(gc, w2, e2); e3 = fmaf(gc, w3, e3);
    f0 = fmaf(gd, w0, f0); f1 = fmaf(gd, w1, f1);
    f2 = fmaf(gd, w2, f2); f3 = fmaf(gd, w3, f3);
  }
  const float* gm = gamma + t * O_N;
  const float* bt = beta + t * O_N;
  gelu_ln_store(a0, a1, a2, a3, gm, bt, out + ((size_t)(b0)*T_N + t) * O_N, lane);
  gelu_ln_store(c0, c1, c2, c3, gm, bt, out + ((size_t)(b0 + 4) * T_N + t) * O_N, lane);
  gelu_ln_store(e0, e1, e2, e3, gm, bt, out + ((size_t)(b0 + 8) * T_N + t) * O_N, lane);
  gelu_ln_store(f0, f1, f2, f3, gm, bt, out + ((size_t)(b0 + 12) * T_N + t) * O_N, lane);
}

// ---------------- launch ----------------
extern "C" void kernel_launch(void* const* d_in, const int* in_sizes, int n_in,
                              void* d_out, int out_size, void* d_ws, size_t ws_size,
                              hipStream_t stream) {
  const float* x = (const float*)d_in[0];
  const float* Wt = (const float*)d_in[1];
  const float* Wd = (const float*)d_in[2];
  const float* bd = (const float*)d_in[3];
  const float* gamma = (const float*)d_in[4];
  const float* beta = (const float*)d_in[5];
  float* out = (float*)d_out;

  char* ws = (char*)d_ws;
  size_t sz_wt = (size_t)T_N * H_N * L_N * 2; // 128 MB
  size_t sz_x = (size_t)B_N * L_N * 2;        // 2 MB
  size_t off_h = sz_wt + sz_x;
  size_t sz_h_f32 = (size_t)B_N * NCOL * 4;   // 256 MB
  size_t sz_h_b16 = (size_t)B_N * NCOL * 2;   // 128 MB
  size_t sz_g = (size_t)B_N * T_N * K_TOP * 4; // 8 MB

  bf16_t* WTb = (bf16_t*)ws;
  bf16_t* Xb = (bf16_t*)(ws + sz_wt);

  cvt_x_kernel<<<B_N * L_N / 1024, 256, 0, stream>>>(x, Xb);
  cvt_w_kernel<<<dim3(H_N / 64, L_N / 64, T_N), 256, 0, stream>>>(Wt, WTb);

  if (ws_size >= off_h + sz_h_f32) {
    float* hidden = (float*)(ws + off_h);
    // g buffer: after hidden if it fits, else overlap WT (dead after gemm1)
    float* gbuf = (ws_size >= off_h + sz_h_f32 + sz_g)
                      ? (float*)(ws + off_h + sz_h_f32)
                      : (float*)ws;
    gemm1_kernel<float><<<4096, 256, 0, stream>>>(Xb, WTb, hidden);
    topk_select_kernel<float><<<dim3(B_N / 4, T_N), 256, 0, stream>>>(hidden, gbuf);
    dense_tail_kernel<<<dim3(B_N / 16, T_N), 256, 0, stream>>>(gbuf, Wd, bd, gamma,
                                                               beta, out);
  } else { // fall back to bf16 hidden (270 MB total ws)
    bf16_t* hidden = (bf16_t*)(ws + off_h);
    float* gbuf = (ws_size >= off_h + sz_h_b16 + sz_g)
                      ? (float*)(ws + off_h + sz_h_b16)
                      : (float*)ws;
    gemm1_kernel<bf16_t><<<4096, 256, 0, stream>>>(Xb, WTb, hidden);
    topk_select_kernel<bf16_t><<<dim3(B_N / 4, T_N), 256, 0, stream>>>(hidden, gbuf);
    dense_tail_kernel<<<dim3(B_N / 16, T_N), 256, 0, stream>>>(gbuf, Wd, bd, gamma,
                                                               beta, out);
  }
}

// Round 4
// 800.457 us; speedup vs baseline: 2.8407x; 2.2602x over previous
//
#include <hip/hip_runtime.h>
#include <hip/hip_bf16.h>
#include <math.h>

typedef __bf16 bf16_t;
typedef __bf16 bf16x2_t __attribute__((ext_vector_type(2)));
typedef __bf16 bf16x4_t __attribute__((ext_vector_type(4)));
typedef __bf16 bf16x8_t __attribute__((ext_vector_type(8)));
typedef float f32x4_t __attribute__((ext_vector_type(4)));

#define B_N 1024
#define L_N 1024
#define T_N 32
#define H_N 2048
#define K_TOP 64
#define O_N 256
#define NCOL (T_N * H_N) /* 65536 */

// VGPR-budget rules on gfx950 (R1-R3 post-mortems):
//   __launch_bounds__(256, w) caps VGPRs at 256/w.
//   FULL UNROLL over a deep load loop (VMEM _or_ LDS) lets the compiler
//   batch loads arbitrarily deep -> pressure exceeds any cap -> scratch
//   spill (R1: 5GB, R2: 4.1GB, R3: 2.9GB phantom traffic). Fix is
//   structural: partial unroll + LDS-broadcast instead of literal-k shfl.

// ---------------- conversion: x -> bf16 ----------------
__global__ __launch_bounds__(256) void cvt_x_kernel(const float* __restrict__ x,
                                                    bf16_t* __restrict__ xb) {
  int i = (blockIdx.x * 256 + threadIdx.x) * 4;
  float4 v = *(const float4*)(x + i);
  bf16x4_t o;
  o[0] = (bf16_t)v.x; o[1] = (bf16_t)v.y; o[2] = (bf16_t)v.z; o[3] = (bf16_t)v.w;
  *(bf16x4_t*)(xb + i) = o;
}

// -------- conversion+transpose: Wt [T,L,H] f32 -> WT [T,H,L] bf16 --------
__global__ __launch_bounds__(256) void cvt_w_kernel(const float* __restrict__ W,
                                                    bf16_t* __restrict__ WT) {
  __shared__ float tile[64][65];
  int t = blockIdx.z;
  int h0 = blockIdx.x * 64;
  int l0 = blockIdx.y * 64;
  const float* src = W + (size_t)t * L_N * H_N;
  int hx = threadIdx.x & 63;
  int ly = threadIdx.x >> 6;
#pragma unroll
  for (int r = 0; r < 64; r += 4)
    tile[ly + r][hx] = src[(size_t)(l0 + ly + r) * H_N + h0 + hx];
  __syncthreads();
  bf16_t* dst = WT + (size_t)t * H_N * L_N;
  int lx = (threadIdx.x & 31) * 2;
  int hy = threadIdx.x >> 5;
#pragma unroll
  for (int r = 0; r < 64; r += 8) {
    int h = hy + r;
    bf16x2_t o;
    o[0] = (bf16_t)tile[lx][h];
    o[1] = (bf16_t)tile[lx + 1][h];
    *(bf16x2_t*)(dst + (size_t)(h0 + h) * L_N + l0 + lx) = o;
  }
}

// ---------------- GEMM1: hidden[b, t*2048+h] = sum_l x[b,l]*W[t,l,h] ----------------
#define BM 128
#define BN 128
#define BK 32

__device__ __forceinline__ void async_load16(const void* g, void* l) {
  __builtin_amdgcn_global_load_lds((const __attribute__((address_space(1))) void*)g,
                                   (__attribute__((address_space(3))) void*)l,
                                   16, 0, 0);
}

template <typename HT>
__global__ __launch_bounds__(256) void gemm1_kernel(const bf16_t* __restrict__ Xb,
                                                    const bf16_t* __restrict__ WT,
                                                    HT* __restrict__ hidden) {
  __shared__ bf16_t As[BM][BK]; // [m][k], row = 64 B
  __shared__ bf16_t Bs[BN][BK]; // [n][k], row = 64 B  (WT is already [n][k] in global)
  int tid = threadIdx.x;
  int wave = tid >> 6;
  int lane = tid & 63;
  int bid = blockIdx.x;
  int m0 = (bid & 7) * BM;      // 8 row tiles over B=1024
  int nbase = (bid >> 3) * BN;  // 512 col tiles over T*H=65536

  const bf16_t* Aptr = Xb + (size_t)m0 * L_N;
  const bf16_t* Bptr = WT + (size_t)nbase * L_N;

  // staging: lane i copies 16 B; wave covers 16 contiguous 64 B LDS rows
  int srow = lane >> 2;
  int scol = lane & 3;
  size_t soff = (size_t)(wave * 16 + srow) * L_N + scol * 8;

  f32x4_t acc[4][4];
  f32x4_t zero = {0.f, 0.f, 0.f, 0.f};
#pragma unroll
  for (int i = 0; i < 4; i++)
#pragma unroll
    for (int j = 0; j < 4; j++) acc[i][j] = zero;

  int wm = wave >> 1, wn = wave & 1;
  int fr = lane & 15;
  int fq = lane >> 4;

  for (int k0 = 0; k0 < L_N; k0 += BK) {
    const bf16_t* ga = Aptr + soff + k0;
    const bf16_t* gb = Bptr + soff + k0;
    async_load16(ga, &As[wave * 16][0]);
    async_load16(ga + 64 * L_N, &As[64 + wave * 16][0]);
    async_load16(gb, &Bs[wave * 16][0]);
    async_load16(gb + 64 * L_N, &Bs[64 + wave * 16][0]);
    __syncthreads();
    bf16x8_t af[4], bfv[4];
#pragma unroll
    for (int i = 0; i < 4; i++)
      af[i] = *(const bf16x8_t*)&As[wm * 64 + i * 16 + fr][fq * 8];
#pragma unroll
    for (int j = 0; j < 4; j++)
      bfv[j] = *(const bf16x8_t*)&Bs[wn * 64 + j * 16 + fr][fq * 8];
#pragma unroll
    for (int i = 0; i < 4; i++)
#pragma unroll
      for (int j = 0; j < 4; j++)
        acc[i][j] = __builtin_amdgcn_mfma_f32_16x16x32_bf16(af[i], bfv[j], acc[i][j], 0, 0, 0);
    __syncthreads();
  }

  // C/D layout: col = lane&15, row = (lane>>4)*4 + r  [verified m89/m91]
#pragma unroll
  for (int i = 0; i < 4; i++) {
    int gm = m0 + wm * 64 + i * 16 + fq * 4;
#pragma unroll
    for (int j = 0; j < 4; j++) {
      int gn = nbase + wn * 64 + j * 16 + fr;
      HT* outp = hidden + (size_t)gm * NCOL + gn;
#pragma unroll
      for (int r = 0; r < 4; r++) outp[(size_t)r * NCOL] = (HT)acc[i][j][r];
    }
  }
}

// ---------------- helpers shared by the tail kernels ----------------

__device__ __forceinline__ float wave_reduce_sum(float v) {
#pragma unroll
  for (int off = 32; off > 0; off >>= 1) v += __shfl_xor(v, off);
  return v;
}

// order-preserving float->uint key and inverse
__device__ __forceinline__ unsigned f2key(float f) {
  unsigned u = __float_as_uint(f);
  return u ^ ((u >> 31) ? 0xFFFFFFFFu : 0x80000000u);
}
__device__ __forceinline__ float key2f(unsigned k) {
  return __uint_as_float(k ^ ((k >> 31) ? 0x80000000u : 0xFFFFFFFFu));
}

__device__ __forceinline__ int lanes_below(unsigned long long m) {
  return (int)__builtin_amdgcn_mbcnt_hi((unsigned)(m >> 32),
                                        __builtin_amdgcn_mbcnt_lo((unsigned)m, 0u));
}

// f32 path: 2 batches of 4x16B loads — staging peak 16 VGPRs on top of key[32]
__device__ __forceinline__ void load_keys(const float* __restrict__ row, int lane,
                                          unsigned key[32]) {
  const float4* r4 = (const float4*)row;
#pragma unroll
  for (int h = 0; h < 2; h++) {
    float4 v[4];
#pragma unroll
    for (int q = 0; q < 4; q++) v[q] = r4[lane + 64 * (h * 4 + q)];
#pragma unroll
    for (int q = 0; q < 4; q++) {
      int o = (h * 4 + q) * 4;
      key[o + 0] = f2key(v[q].x);
      key[o + 1] = f2key(v[q].y);
      key[o + 2] = f2key(v[q].z);
      key[o + 3] = f2key(v[q].w);
    }
  }
}

__device__ __forceinline__ void load_keys(const bf16_t* __restrict__ row, int lane,
                                          unsigned key[32]) {
  const bf16x8_t* r8 = (const bf16x8_t*)row;
#pragma unroll
  for (int h = 0; h < 2; h++) {
    bf16x8_t v[2];
#pragma unroll
    for (int q = 0; q < 2; q++) v[q] = r8[lane + 64 * (h * 2 + q)];
#pragma unroll
    for (int q = 0; q < 2; q++)
#pragma unroll
      for (int j = 0; j < 8; j++) key[(h * 2 + q) * 8 + j] = f2key((float)v[q][j]);
  }
}

// ---------------- kernel A: top-64 select + sort -> g[B,T,64] f32 ----------------
// (256,3) = 85-VGPR budget; measured need ~60 (key 32 + staging 16 + temps ~12).
template <typename HT>
__global__ __launch_bounds__(256, 3) void topk_select_kernel(
    const HT* __restrict__ hidden, float* __restrict__ g_out) {
  __shared__ unsigned slots[4][K_TOP];
  int t = blockIdx.y;
  int wave = threadIdx.x >> 6;
  int lane = threadIdx.x & 63;
  int b = blockIdx.x * 4 + wave;

  unsigned key[32];
  load_keys(hidden + (size_t)b * NCOL + (size_t)t * H_N, lane, key);

  // exact 64th-largest key: largest thr with count(key >= thr) >= 64
  unsigned thr = 0;
  for (int bit = 31; bit >= 0; --bit) {
    unsigned cand = thr | (1u << bit);
    int c = 0;
#pragma unroll
    for (int i = 0; i < 32; i++) c += (int)__popcll(__ballot(key[i] >= cand));
    if (c >= K_TOP) thr = cand; // wave-uniform
  }

  // compaction via ballot prefix (no atomics, wave-local LDS only)
  int base = 0;
#pragma unroll
  for (int i = 0; i < 32; i++) {
    bool p = key[i] > thr;
    unsigned long long m = __ballot(p);
    if (p) slots[wave][base + lanes_below(m)] = key[i];
    base += (int)__popcll(m);
  }
#pragma unroll
  for (int i = 0; i < 32; i++) {
    bool p = key[i] == thr;
    unsigned long long m = __ballot(p);
    if (p) {
      int pos = base + lanes_below(m);
      if (pos < K_TOP) slots[wave][pos] = key[i];
    }
    base += (int)__popcll(m);
  }

  // 64-lane register bitonic sort, descending (unsigned keys)
  unsigned g = slots[wave][lane];
#pragma unroll
  for (int k = 2; k <= 64; k <<= 1) {
#pragma unroll
    for (int j = k >> 1; j > 0; j >>= 1) {
      unsigned other = (unsigned)__shfl_xor((int)g, j);
      bool keep_max = (((lane & k) == 0) != ((lane & j) != 0));
      unsigned mx = g > other ? g : other;
      unsigned mn = g > other ? other : g;
      g = keep_max ? mx : mn;
    }
  }
  g_out[((size_t)b * T_N + t) * K_TOP + lane] = key2f(g);
}

// ---------------- kernel B: dense + GELU + LN from g ----------------

// Lane owns 4 CONSECUTIVE output cols (4*lane..4*lane+3): W reads are one
// conflict-free ds_read_b128 (16-lane group covers all 32 banks once), and
// bias/gamma/beta/out are float4 accesses.
__device__ __forceinline__ void gelu_ln_store4(f32x4_t y,
                                               const float* __restrict__ gm,
                                               const float* __restrict__ bt,
                                               float* __restrict__ op, int lane) {
  const float is2 = 0.70710678118654752f;
#pragma unroll
  for (int j = 0; j < 4; j++) y[j] = 0.5f * y[j] * (1.f + erff(y[j] * is2));
  float mean = wave_reduce_sum(y[0] + y[1] + y[2] + y[3]) * (1.f / 256.f);
  f32x4_t d;
#pragma unroll
  for (int j = 0; j < 4; j++) d[j] = y[j] - mean;
  float var = wave_reduce_sum(d[0] * d[0] + d[1] * d[1] + d[2] * d[2] + d[3] * d[3]) *
              (1.f / 256.f);
  float rstd = rsqrtf(var + 1e-6f);
  f32x4_t gmv = *(const f32x4_t*)(gm + 4 * lane);
  f32x4_t btv = *(const f32x4_t*)(bt + 4 * lane);
  f32x4_t o;
#pragma unroll
  for (int j = 0; j < 4; j++) o[j] = d[j] * rstd * gmv[j] + btv[j];
  *(f32x4_t*)(op + 4 * lane) = o;
}

// Wd tile (64x256 f32 = 64 KB) in LDS; g broadcast via uniform-address LDS
// reads (replaces the literal-k shfl that forced full unroll). Outer loop is
// #pragma unroll 1: load window is structurally 8 ds_read_b128 + 16 acc
// (~60 regs) -> spill mechanism removed, not tuned around.
__global__ __launch_bounds__(256, 2) void dense_tail_kernel(
    const float* __restrict__ g_in, const float* __restrict__ Wd,
    const float* __restrict__ bd, const float* __restrict__ gamma,
    const float* __restrict__ beta, float* __restrict__ out) {
  __shared__ f32x4_t wlds4[K_TOP * O_N / 4]; // 64 KB, layout [k][64 float4]
  __shared__ f32x4_t glds4[4][4][K_TOP / 4]; // 4 KB: [wave][row][k-chunk]
  int t = blockIdx.y;
  int wave = threadIdx.x >> 6;
  int lane = threadIdx.x & 63;
  int b0 = blockIdx.x * 16 + wave; // rows b0, b0+4, b0+8, b0+12

  // cooperative Wd stage: 4096 float4, 16 per thread (straight copy)
  {
    const f32x4_t* src = (const f32x4_t*)(Wd + (size_t)t * K_TOP * O_N);
#pragma unroll
    for (int i = 0; i < 16; i++)
      wlds4[threadIdx.x + 256 * i] = src[threadIdx.x + 256 * i];
  }

  // stage this wave's 4 g rows into LDS (lane k holds g[k])
  {
    float* g0 = (float*)&glds4[wave][0][0];
    float* g1 = (float*)&glds4[wave][1][0];
    float* g2 = (float*)&glds4[wave][2][0];
    float* g3 = (float*)&glds4[wave][3][0];
    g0[lane] = g_in[((size_t)(b0)*T_N + t) * K_TOP + lane];
    g1[lane] = g_in[((size_t)(b0 + 4) * T_N + t) * K_TOP + lane];
    g2[lane] = g_in[((size_t)(b0 + 8) * T_N + t) * K_TOP + lane];
    g3[lane] = g_in[((size_t)(b0 + 12) * T_N + t) * K_TOP + lane];
  }

  const float* bdt = bd + t * O_N;
  f32x4_t bb = *(const f32x4_t*)(bdt + 4 * lane);
  f32x4_t aA = bb, aB = bb, aC = bb, aD = bb;

  __syncthreads();

#pragma unroll 1
  for (int c = 0; c < K_TOP / 4; c++) {
    f32x4_t gA = glds4[wave][0][c]; // uniform address -> broadcast, no conflict
    f32x4_t gB = glds4[wave][1][c];
    f32x4_t gC = glds4[wave][2][c];
    f32x4_t gD = glds4[wave][3][c];
#pragma unroll
    for (int kk = 0; kk < 4; kk++) {
      f32x4_t w = wlds4[(c * 4 + kk) * 64 + lane];
#pragma unroll
      for (int j = 0; j < 4; j++) {
        aA[j] = fmaf(gA[kk], w[j], aA[j]);
        aB[j] = fmaf(gB[kk], w[j], aB[j]);
        aC[j] = fmaf(gC[kk], w[j], aC[j]);
        aD[j] = fmaf(gD[kk], w[j], aD[j]);
      }
    }
  }

  const float* gm = gamma + t * O_N;
  const float* bt = beta + t * O_N;
  gelu_ln_store4(aA, gm, bt, out + ((size_t)(b0)*T_N + t) * O_N, lane);
  gelu_ln_store4(aB, gm, bt, out + ((size_t)(b0 + 4) * T_N + t) * O_N, lane);
  gelu_ln_store4(aC, gm, bt, out + ((size_t)(b0 + 8) * T_N + t) * O_N, lane);
  gelu_ln_store4(aD, gm, bt, out + ((size_t)(b0 + 12) * T_N + t) * O_N, lane);
}

// ---------------- launch ----------------
extern "C" void kernel_launch(void* const* d_in, const int* in_sizes, int n_in,
                              void* d_out, int out_size, void* d_ws, size_t ws_size,
                              hipStream_t stream) {
  const float* x = (const float*)d_in[0];
  const float* Wt = (const float*)d_in[1];
  const float* Wd = (const float*)d_in[2];
  const float* bd = (const float*)d_in[3];
  const float* gamma = (const float*)d_in[4];
  const float* beta = (const float*)d_in[5];
  float* out = (float*)d_out;

  char* ws = (char*)d_ws;
  size_t sz_wt = (size_t)T_N * H_N * L_N * 2; // 128 MB
  size_t sz_x = (size_t)B_N * L_N * 2;        // 2 MB
  size_t off_h = sz_wt + sz_x;
  size_t sz_h_f32 = (size_t)B_N * NCOL * 4;   // 256 MB
  size_t sz_h_b16 = (size_t)B_N * NCOL * 2;   // 128 MB
  size_t sz_g = (size_t)B_N * T_N * K_TOP * 4; // 8 MB

  bf16_t* WTb = (bf16_t*)ws;
  bf16_t* Xb = (bf16_t*)(ws + sz_wt);

  cvt_x_kernel<<<B_N * L_N / 1024, 256, 0, stream>>>(x, Xb);
  cvt_w_kernel<<<dim3(H_N / 64, L_N / 64, T_N), 256, 0, stream>>>(Wt, WTb);

  if (ws_size >= off_h + sz_h_f32) {
    float* hidden = (float*)(ws + off_h);
    // g buffer: after hidden if it fits, else overlap WT (dead after gemm1)
    float* gbuf = (ws_size >= off_h + sz_h_f32 + sz_g)
                      ? (float*)(ws + off_h + sz_h_f32)
                      : (float*)ws;
    gemm1_kernel<float><<<4096, 256, 0, stream>>>(Xb, WTb, hidden);
    topk_select_kernel<float><<<dim3(B_N / 4, T_N), 256, 0, stream>>>(hidden, gbuf);
    dense_tail_kernel<<<dim3(B_N / 16, T_N), 256, 0, stream>>>(gbuf, Wd, bd, gamma,
                                                               beta, out);
  } else { // fall back to bf16 hidden (270 MB total ws)
    bf16_t* hidden = (bf16_t*)(ws + off_h);
    float* gbuf = (ws_size >= off_h + sz_h_b16 + sz_g)
                      ? (float*)(ws + off_h + sz_h_b16)
                      : (float*)ws;
    gemm1_kernel<bf16_t><<<4096, 256, 0, stream>>>(Xb, WTb, hidden);
    topk_select_kernel<bf16_t><<<dim3(B_N / 4, T_N), 256, 0, stream>>>(hidden, gbuf);
    dense_tail_kernel<<<dim3(B_N / 16, T_N), 256, 0, stream>>>(gbuf, Wd, bd, gamma,
                                                               beta, out);
  }
}